// Round 1
// baseline (4112.146 us; speedup 1.0000x reference)
//
#include <hip/hip_runtime.h>

#define NB  8      // batch elements per block
#define TPB 256    // threads per block
#define T_  256
#define F_  32
#define H1  64
#define H2  32

__device__ __forceinline__ float sigmoid_fast(float x) {
    return __fdividef(1.f, 1.f + __expf(-x));
}
__device__ __forceinline__ float tanh_fast(float x) {
    // tanh(x) = 1 - 2/(exp(2x)+1); saturates correctly at +/-inf
    float e = __expf(2.f * x);
    return 1.f - __fdividef(2.f, e + 1.f);
}

__global__ __launch_bounds__(TPB, 2) void lstm_fused(
    const float* __restrict__ x,      // [4096,256,32]
    const float* __restrict__ W_ih1,  // [256,32]
    const float* __restrict__ W_hh1,  // [256,64]
    const float* __restrict__ b_ih1,  // [256]
    const float* __restrict__ b_hh1,  // [256]
    const float* __restrict__ W_ih2,  // [128,64]
    const float* __restrict__ W_hh2,  // [128,32]
    const float* __restrict__ b_ih2,  // [128]
    const float* __restrict__ b_hh2,  // [128]
    const float* __restrict__ W_fc1,  // [16,32]
    const float* __restrict__ b_fc1,  // [16]
    const float* __restrict__ W_fc2,  // [1,16]
    const float* __restrict__ b_fc2,  // [1]
    float* __restrict__ out)          // [4096]
{
    const int tid = threadIdx.x;
    const int b0  = blockIdx.x * NB;

    // v1 = [x_t(32) | h1(64)], v2 = [h1(64) | h2(32)] per batch element
    __shared__ float v1[NB][96];
    __shared__ float v2[NB][96];
    // gate preact partials; row stride 12 floats (48B) -> conflict-free b128
    __shared__ float p1[2][256][12];
    __shared__ float p2[4][128][12];
    __shared__ float hd[NB][16];

    // ---- layer-1 row ownership: rows rp, rp+128; k-half kh (48 each) ----
    const int rp = tid & 127;
    const int kh = tid >> 7;
    const int koff1 = kh * 48;
    float w1[2][48];
    float bias1[2];
    #pragma unroll
    for (int rr = 0; rr < 2; ++rr) {
        const int r = rp + rr * 128;
        #pragma unroll
        for (int kk = 0; kk < 48; ++kk) {
            const int k = koff1 + kk;
            w1[rr][kk] = (k < 32) ? W_ih1[r * 32 + k] : W_hh1[r * 64 + (k - 32)];
        }
        bias1[rr] = (kh == 0) ? (b_ih1[r] + b_hh1[r]) : 0.f;
    }

    // ---- layer-2 row ownership: rows rp2, rp2+64; k-quarter kq (24 each) ----
    const int rp2 = tid & 63;
    const int kq  = tid >> 6;
    const int koff2 = kq * 24;
    float w2[2][24];
    float bias2[2];
    #pragma unroll
    for (int rr = 0; rr < 2; ++rr) {
        const int r = rp2 + rr * 64;
        #pragma unroll
        for (int kk = 0; kk < 24; ++kk) {
            const int k = koff2 + kk;
            w2[rr][kk] = (k < 64) ? W_ih2[r * 64 + k] : W_hh2[r * 32 + (k - 64)];
        }
        bias2[rr] = (kq == 0) ? (b_ih2[r] + b_hh2[r]) : 0.f;
    }

    // ---- state ownership for gate-combine phases ----
    const int u1  = tid & 63;   // layer-1 hidden unit
    const int bp1 = tid >> 6;   // batch pair -> b in {2*bp1, 2*bp1+1}
    float c1s[2] = {0.f, 0.f};
    const int u2  = tid & 31;   // layer-2 hidden unit
    const int bq2 = tid >> 5;   // batch element
    float c2s = 0.f;

    // ---- init: zero h regions, stage x_0, prefetch x_1 ----
    const int xb = tid >> 5, xf = tid & 31;
    const size_t xbase = (size_t)(b0 + xb) * (T_ * F_) + xf;
    for (int i = tid; i < NB * 96; i += TPB) (&v1[0][0])[i] = 0.f;
    for (int i = tid; i < NB * 96; i += TPB) (&v2[0][0])[i] = 0.f;
    float xn = x[xbase];            // x_0
    __syncthreads();
    v1[xb][xf] = xn;                // stage x_0
    xn = x[xbase + F_];             // prefetch x_1
    __syncthreads();

    for (int t = 0; t < T_; ++t) {
        // ===== phase A: layer-1 gate dots (reads v1) =====
        float acc[2][NB];
        #pragma unroll
        for (int b = 0; b < NB; ++b) { acc[0][b] = bias1[0]; acc[1][b] = bias1[1]; }
        #pragma unroll
        for (int kc = 0; kc < 12; ++kc) {
            #pragma unroll
            for (int b = 0; b < NB; ++b) {
                const float4 v = *(const float4*)&v1[b][koff1 + kc * 4];
                acc[0][b] = fmaf(w1[0][4*kc+0], v.x, acc[0][b]);
                acc[0][b] = fmaf(w1[0][4*kc+1], v.y, acc[0][b]);
                acc[0][b] = fmaf(w1[0][4*kc+2], v.z, acc[0][b]);
                acc[0][b] = fmaf(w1[0][4*kc+3], v.w, acc[0][b]);
                acc[1][b] = fmaf(w1[1][4*kc+0], v.x, acc[1][b]);
                acc[1][b] = fmaf(w1[1][4*kc+1], v.y, acc[1][b]);
                acc[1][b] = fmaf(w1[1][4*kc+2], v.z, acc[1][b]);
                acc[1][b] = fmaf(w1[1][4*kc+3], v.w, acc[1][b]);
            }
        }
        #pragma unroll
        for (int rr = 0; rr < 2; ++rr) {
            float* dst = &p1[kh][rp + rr * 128][0];
            *(float4*)&dst[0] = make_float4(acc[rr][0], acc[rr][1], acc[rr][2], acc[rr][3]);
            *(float4*)&dst[4] = make_float4(acc[rr][4], acc[rr][5], acc[rr][6], acc[rr][7]);
        }
        __syncthreads();   // B1

        // ===== phase B: layer-1 gate combine (all 256 threads: 64 units x 8 b) =====
        #pragma unroll
        for (int j = 0; j < 2; ++j) {
            const int b = bp1 * 2 + j;
            float gi = p1[0][      u1][b] + p1[1][      u1][b];
            float gf = p1[0][ 64 + u1][b] + p1[1][ 64 + u1][b];
            float gg = p1[0][128 + u1][b] + p1[1][128 + u1][b];
            float go = p1[0][192 + u1][b] + p1[1][192 + u1][b];
            float i_ = sigmoid_fast(gi);
            float f_ = sigmoid_fast(gf);
            float g_ = tanh_fast(gg);
            float o_ = sigmoid_fast(go);
            float c  = fmaf(f_, c1s[j], i_ * g_);
            c1s[j] = c;
            float h  = o_ * tanh_fast(c);
            v1[b][32 + u1] = h;   // h1 for next step's layer-1 input
            v2[b][u1]      = h;   // h1 for this step's layer-2 input
        }
        // stage x_{t+1}, prefetch x_{t+2}
        v1[xb][xf] = xn;
        {
            const int t2 = (t + 2 < T_) ? (t + 2) : (T_ - 1);
            xn = x[xbase + (size_t)t2 * F_];
        }
        __syncthreads();   // B2

        // ===== phase C: layer-2 gate dots (reads v2) =====
        float a2[2][NB];
        #pragma unroll
        for (int b = 0; b < NB; ++b) { a2[0][b] = bias2[0]; a2[1][b] = bias2[1]; }
        #pragma unroll
        for (int kc = 0; kc < 6; ++kc) {
            #pragma unroll
            for (int b = 0; b < NB; ++b) {
                const float4 v = *(const float4*)&v2[b][koff2 + kc * 4];
                a2[0][b] = fmaf(w2[0][4*kc+0], v.x, a2[0][b]);
                a2[0][b] = fmaf(w2[0][4*kc+1], v.y, a2[0][b]);
                a2[0][b] = fmaf(w2[0][4*kc+2], v.z, a2[0][b]);
                a2[0][b] = fmaf(w2[0][4*kc+3], v.w, a2[0][b]);
                a2[1][b] = fmaf(w2[1][4*kc+0], v.x, a2[1][b]);
                a2[1][b] = fmaf(w2[1][4*kc+1], v.y, a2[1][b]);
                a2[1][b] = fmaf(w2[1][4*kc+2], v.z, a2[1][b]);
                a2[1][b] = fmaf(w2[1][4*kc+3], v.w, a2[1][b]);
            }
        }
        #pragma unroll
        for (int rr = 0; rr < 2; ++rr) {
            float* dst = &p2[kq][rp2 + rr * 64][0];
            *(float4*)&dst[0] = make_float4(a2[rr][0], a2[rr][1], a2[rr][2], a2[rr][3]);
            *(float4*)&dst[4] = make_float4(a2[rr][4], a2[rr][5], a2[rr][6], a2[rr][7]);
        }
        __syncthreads();   // B3

        // ===== phase D: layer-2 gate combine (32 units x 8 b = 256 threads) =====
        {
            const int b = bq2;
            float gi = p2[0][     u2][b] + p2[1][     u2][b] + p2[2][     u2][b] + p2[3][     u2][b];
            float gf = p2[0][32 + u2][b] + p2[1][32 + u2][b] + p2[2][32 + u2][b] + p2[3][32 + u2][b];
            float gg = p2[0][64 + u2][b] + p2[1][64 + u2][b] + p2[2][64 + u2][b] + p2[3][64 + u2][b];
            float go = p2[0][96 + u2][b] + p2[1][96 + u2][b] + p2[2][96 + u2][b] + p2[3][96 + u2][b];
            float i_ = sigmoid_fast(gi);
            float f_ = sigmoid_fast(gf);
            float g_ = tanh_fast(gg);
            float o_ = sigmoid_fast(go);
            float c  = fmaf(f_, c2s, i_ * g_);
            c2s = c;
            float h  = o_ * tanh_fast(c);
            v2[b][64 + u2] = h;   // h2 state
        }
        // no barrier needed here: next reader of v2[.. 64+] is phase C after B1,B2
    }

    __syncthreads();
    // ===== head: fc1 (16, relu) then fc2 (1) =====
    if (tid < NB * 16) {
        const int b = tid >> 4, u = tid & 15;
        float a = b_fc1[u];
        #pragma unroll
        for (int k = 0; k < 32; ++k) a = fmaf(W_fc1[u * 32 + k], v2[b][64 + k], a);
        hd[b][u] = fmaxf(a, 0.f);
    }
    __syncthreads();
    if (tid < NB) {
        float a = b_fc2[0];
        #pragma unroll
        for (int k = 0; k < 16; ++k) a = fmaf(W_fc2[k], hd[tid][k], a);
        out[b0 + tid] = a;
    }
}

extern "C" void kernel_launch(void* const* d_in, const int* in_sizes, int n_in,
                              void* d_out, int out_size, void* d_ws, size_t ws_size,
                              hipStream_t stream) {
    const float* x     = (const float*)d_in[0];
    const float* W_ih1 = (const float*)d_in[1];
    const float* W_hh1 = (const float*)d_in[2];
    const float* b_ih1 = (const float*)d_in[3];
    const float* b_hh1 = (const float*)d_in[4];
    const float* W_ih2 = (const float*)d_in[5];
    const float* W_hh2 = (const float*)d_in[6];
    const float* b_ih2 = (const float*)d_in[7];
    const float* b_hh2 = (const float*)d_in[8];
    const float* W_fc1 = (const float*)d_in[9];
    const float* b_fc1 = (const float*)d_in[10];
    const float* W_fc2 = (const float*)d_in[11];
    const float* b_fc2 = (const float*)d_in[12];
    float* out = (float*)d_out;

    const int B = in_sizes[0] / (T_ * F_);   // 4096
    dim3 grid(B / NB), block(TPB);
    hipLaunchKernelGGL(lstm_fused, grid, block, 0, stream,
                       x, W_ih1, W_hh1, b_ih1, b_hh1,
                       W_ih2, W_hh2, b_ih2, b_hh2,
                       W_fc1, b_fc1, W_fc2, b_fc2, out);
}

// Round 2
// 3566.156 us; speedup vs baseline: 1.1531x; 1.1531x over previous
//
#include <hip/hip_runtime.h>

#define TPB    512
#define NB     8      // batch elements per block
#define T_     256
#define F_     32
#define ROWPAD 104    // floats per batch-row in LDS (16B-aligned, bank-conflict-free)
#define BUFSZ  (NB * ROWPAD)   // 832 floats per buffer

__device__ __forceinline__ float sigmoid_fast(float x) {
    return __fdividef(1.f, 1.f + __expf(-x));
}
__device__ __forceinline__ float tanh_fast(float x) {
    float e = __expf(2.f * x);
    return 1.f - __fdividef(2.f, e + 1.f);
}

// DPP cross-lane move: returns src from lane mapped by CTRL (within row of 16)
template<int CTRL>
__device__ __forceinline__ float dppf(float v) {
    return __int_as_float(__builtin_amdgcn_update_dpp(
        0, __float_as_int(v), CTRL, 0xF, 0xF, true));
}
#define DPP_XOR1 0xB1   // quad_perm [1,0,3,2] : lane ^ 1
#define DPP_XOR2 0x4E   // quad_perm [2,3,0,1] : lane ^ 2
#define DPP_ROR8 0x128  // row_ror:8          : lane ^ 8 (within row16)

__device__ __forceinline__ float swz_xor16(float v) {
    // ds_swizzle BitMode: xor_mask=16, and_mask=0x1F -> lane ^ 16 (within 32)
    return __int_as_float(__builtin_amdgcn_ds_swizzle(__float_as_int(v), 0x401F));
}

__global__ __launch_bounds__(TPB, 4) void lstm_fused(
    const float* __restrict__ x,      // [4096,256,32]
    const float* __restrict__ W_ih1,  // [256,32]
    const float* __restrict__ W_hh1,  // [256,64]
    const float* __restrict__ b_ih1,  // [256]
    const float* __restrict__ b_hh1,  // [256]
    const float* __restrict__ W_ih2,  // [128,64]
    const float* __restrict__ W_hh2,  // [128,32]
    const float* __restrict__ b_ih2,  // [128]
    const float* __restrict__ b_hh2,  // [128]
    const float* __restrict__ W_fc1,  // [16,32]
    const float* __restrict__ b_fc1,  // [16]
    const float* __restrict__ W_fc2,  // [1,16]
    const float* __restrict__ b_fc2,  // [1]
    float* __restrict__ out)          // [4096]
{
    const int tid  = threadIdx.x;
    const int lane = tid & 63;
    const int wid  = tid >> 6;
    const int b0   = blockIdx.x * NB;

    // v1 = [x_t(32) | h1(64)], v2 = [h1(64) | h2(32)], double-buffered
    __shared__ float v1s[2 * BUFSZ];
    __shared__ float v2s[2 * BUFSZ];
    __shared__ float hd[NB][16];

    // ---- layer-1 mapping: kq from lane bits {0,1,3}; u from bits {2,4,5}+wid ----
    const int kq = (lane & 3) | (((lane >> 3) & 1) << 2);                       // 0..7
    const int u  = ((lane >> 2) & 1) | (((lane >> 4) & 3) << 1) | (wid << 3);   // 0..63
    // ---- layer-2 mapping: kq2 from lane bits {0,1,3,4}; u2 from bits {2,5}+wid ----
    const int kq2 = (lane & 3) | (((lane >> 3) & 3) << 2);                      // 0..15
    const int u2  = ((lane >> 2) & 1) | (((lane >> 5) & 1) << 1) | (wid << 2);  // 0..31
    const int kp2 = kq2 & 7;

    // ---- weights in registers: all 4 gates of unit u (L1) / u2 (L2), one k-slice ----
    float w1[4][12];
    float bias1[4];
    #pragma unroll
    for (int g = 0; g < 4; ++g) {
        const int r = u + 64 * g;
        bias1[g] = b_ih1[r] + b_hh1[r];
        #pragma unroll
        for (int kk = 0; kk < 12; ++kk) {
            const int k = 12 * kq + kk;
            w1[g][kk] = (k < 32) ? W_ih1[r * 32 + k] : W_hh1[r * 64 + (k - 32)];
        }
    }
    float w2[4][6];
    float bias2[4];
    #pragma unroll
    for (int g = 0; g < 4; ++g) {
        const int r = u2 + 32 * g;
        bias2[g] = b_ih2[r] + b_hh2[r];
        #pragma unroll
        for (int kk = 0; kk < 6; ++kk) {
            const int k = 6 * kq2 + kk;
            w2[g][kk] = (k < 64) ? W_ih2[r * 64 + k] : W_hh2[r * 32 + (k - 64)];
        }
    }

    // ---- init: zero both buffers, stage x0, prefetch x1 ----
    for (int i = tid; i < 2 * BUFSZ; i += TPB) { v1s[i] = 0.f; v2s[i] = 0.f; }
    const int  xb   = tid >> 5, xf = tid & 31;
    const bool xact = tid < NB * F_;   // 256 threads stage x
    const size_t xbase = (size_t)(b0 + xb) * (T_ * F_) + xf;
    float xn = 0.f;
    __syncthreads();
    if (xact) {
        v1s[xb * ROWPAD + xf] = x[xbase];   // x(0) -> buffer 0
        xn = x[xbase + F_];                 // prefetch x(1)
    }
    __syncthreads();

    float c1 = 0.f, c2 = 0.f;

    #pragma unroll 2
    for (int t = 0; t < T_; ++t) {
        const int cur = t & 1;
        const float* v1c  = v1s + cur * BUFSZ;          // A reads
        float*       v1n  = v1s + (cur ^ 1) * BUFSZ;    // A writes h1, x(t+1)
        const float* v2r  = v2s + (cur ^ 1) * BUFSZ;    // C reads (h1(t) + h2(t-1))
        float*       v2wA = v2s + (cur ^ 1) * BUFSZ;    // A writes h1
        float*       v2wC = v2s + cur * BUFSZ;          // C writes h2

        // ===== layer-1 dots: acc[g][r] accumulates batch b = r ^ kq =====
        float acc[4][8];
        #pragma unroll
        for (int g = 0; g < 4; ++g)
            #pragma unroll
            for (int r = 0; r < 8; ++r) acc[g][r] = 0.f;
        #pragma unroll
        for (int j = 0; j < 3; ++j) {
            #pragma unroll
            for (int r = 0; r < 8; ++r) {
                const float4 v = *(const float4*)&v1c[(r ^ kq) * ROWPAD + 12 * kq + 4 * j];
                #pragma unroll
                for (int g = 0; g < 4; ++g) {
                    acc[g][r] = fmaf(w1[g][4 * j + 0], v.x, acc[g][r]);
                    acc[g][r] = fmaf(w1[g][4 * j + 1], v.y, acc[g][r]);
                    acc[g][r] = fmaf(w1[g][4 * j + 2], v.z, acc[g][r]);
                    acc[g][r] = fmaf(w1[g][4 * j + 3], v.w, acc[g][r]);
                }
            }
        }
        // stage x(t+1) into next buffer; prefetch x(t+2)
        if (xact) {
            v1n[xb * ROWPAD + xf] = xn;
            const int tn = (t + 2 < T_) ? t + 2 : T_ - 1;
            xn = x[xbase + (size_t)tn * F_];
        }
        // ===== in-register k-reduce (lanes kq^1, kq^2, kq^4 hold slots r^1,r^2,r^4) =====
        #pragma unroll
        for (int g = 0; g < 4; ++g) {
            acc[g][0] += dppf<DPP_XOR1>(acc[g][1]);
            acc[g][2] += dppf<DPP_XOR1>(acc[g][3]);
            acc[g][4] += dppf<DPP_XOR1>(acc[g][5]);
            acc[g][6] += dppf<DPP_XOR1>(acc[g][7]);
            acc[g][0] += dppf<DPP_XOR2>(acc[g][2]);
            acc[g][4] += dppf<DPP_XOR2>(acc[g][6]);
            acc[g][0] += dppf<DPP_ROR8>(acc[g][4]);
        }
        // ===== layer-1 combine: this lane owns (unit u, batch b = kq) =====
        {
            const float i_ = sigmoid_fast(acc[0][0] + bias1[0]);
            const float f_ = sigmoid_fast(acc[1][0] + bias1[1]);
            const float g_ = tanh_fast   (acc[2][0] + bias1[2]);
            const float o_ = sigmoid_fast(acc[3][0] + bias1[3]);
            c1 = fmaf(f_, c1, i_ * g_);
            const float h1 = o_ * tanh_fast(c1);
            v1n [kq * ROWPAD + 32 + u] = h1;
            v2wA[kq * ROWPAD + u]      = h1;
        }
        __syncthreads();   // the ONLY barrier per step

        // ===== layer-2 dots: a2[g][r] accumulates batch b = r ^ kp2 =====
        float a2[4][8];
        #pragma unroll
        for (int g = 0; g < 4; ++g)
            #pragma unroll
            for (int r = 0; r < 8; ++r) a2[g][r] = 0.f;
        #pragma unroll
        for (int j = 0; j < 3; ++j) {
            #pragma unroll
            for (int r = 0; r < 8; ++r) {
                const float2 v = *(const float2*)&v2r[(r ^ kp2) * ROWPAD + 6 * kq2 + 2 * j];
                #pragma unroll
                for (int g = 0; g < 4; ++g) {
                    a2[g][r] = fmaf(w2[g][2 * j + 0], v.x, a2[g][r]);
                    a2[g][r] = fmaf(w2[g][2 * j + 1], v.y, a2[g][r]);
                }
            }
        }
        // reduce over 16 k-lanes: 3 DPP halvings + final xor16 via ds_swizzle
        #pragma unroll
        for (int g = 0; g < 4; ++g) {
            a2[g][0] += dppf<DPP_XOR1>(a2[g][1]);
            a2[g][2] += dppf<DPP_XOR1>(a2[g][3]);
            a2[g][4] += dppf<DPP_XOR1>(a2[g][5]);
            a2[g][6] += dppf<DPP_XOR1>(a2[g][7]);
            a2[g][0] += dppf<DPP_XOR2>(a2[g][2]);
            a2[g][4] += dppf<DPP_XOR2>(a2[g][6]);
            a2[g][0] += dppf<DPP_ROR8>(a2[g][4]);
            a2[g][0] += swz_xor16(a2[g][0]);
        }
        // ===== layer-2 combine: lane owns (u2, b = kp2); lanes kq2>=8 are duplicates =====
        {
            const float i_ = sigmoid_fast(a2[0][0] + bias2[0]);
            const float f_ = sigmoid_fast(a2[1][0] + bias2[1]);
            const float g_ = tanh_fast   (a2[2][0] + bias2[2]);
            const float o_ = sigmoid_fast(a2[3][0] + bias2[3]);
            c2 = fmaf(f_, c2, i_ * g_);
            const float h2 = o_ * tanh_fast(c2);
            if (!(kq2 & 8)) v2wC[kp2 * ROWPAD + 64 + u2] = h2;
        }
        // no barrier: next A touches only v1; C(t)'s v2 writes cross next step's barrier
    }

    __syncthreads();
    // ===== head: fc1(16)+relu, fc2(1). Final h2 sits in buffer (T_-1)&1 =====
    const float* v2f = v2s + ((T_ - 1) & 1) * BUFSZ;
    if (tid < NB * 16) {
        const int b = tid >> 4, uu = tid & 15;
        float a = b_fc1[uu];
        #pragma unroll
        for (int k = 0; k < 32; ++k)
            a = fmaf(W_fc1[uu * 32 + k], v2f[b * ROWPAD + 64 + k], a);
        hd[b][uu] = fmaxf(a, 0.f);
    }
    __syncthreads();
    if (tid < NB) {
        float a = b_fc2[0];
        #pragma unroll
        for (int k = 0; k < 16; ++k) a = fmaf(W_fc2[k], hd[tid][k], a);
        out[b0 + tid] = a;
    }
}

extern "C" void kernel_launch(void* const* d_in, const int* in_sizes, int n_in,
                              void* d_out, int out_size, void* d_ws, size_t ws_size,
                              hipStream_t stream) {
    const float* x     = (const float*)d_in[0];
    const float* W_ih1 = (const float*)d_in[1];
    const float* W_hh1 = (const float*)d_in[2];
    const float* b_ih1 = (const float*)d_in[3];
    const float* b_hh1 = (const float*)d_in[4];
    const float* W_ih2 = (const float*)d_in[5];
    const float* W_hh2 = (const float*)d_in[6];
    const float* b_ih2 = (const float*)d_in[7];
    const float* b_hh2 = (const float*)d_in[8];
    const float* W_fc1 = (const float*)d_in[9];
    const float* b_fc1 = (const float*)d_in[10];
    const float* W_fc2 = (const float*)d_in[11];
    const float* b_fc2 = (const float*)d_in[12];
    float* out = (float*)d_out;

    const int B = in_sizes[0] / (T_ * F_);   // 4096
    dim3 grid(B / NB), block(TPB);
    hipLaunchKernelGGL(lstm_fused, grid, block, 0, stream,
                       x, W_ih1, W_hh1, b_ih1, b_hh1,
                       W_ih2, W_hh2, b_ih2, b_hh2,
                       W_fc1, b_fc1, W_fc2, b_fc2, out);
}

// Round 3
// 1493.305 us; speedup vs baseline: 2.7537x; 2.3881x over previous
//
#include <hip/hip_runtime.h>

#define TPB    512
#define NB     8      // batch elements per block
#define T_     256
#define F_     32
#define ROWPAD 104    // floats per batch-row in LDS (16B-aligned, bank-conflict-free)
#define BUFSZ  (NB * ROWPAD)   // 832 floats per buffer

__device__ __forceinline__ float sigmoid_fast(float x) {
    return __fdividef(1.f, 1.f + __expf(-x));
}
__device__ __forceinline__ float tanh_fast(float x) {
    float e = __expf(2.f * x);
    return 1.f - __fdividef(2.f, e + 1.f);
}

// DPP cross-lane move: returns src from lane mapped by CTRL (within row of 16)
template<int CTRL>
__device__ __forceinline__ float dppf(float v) {
    return __int_as_float(__builtin_amdgcn_update_dpp(
        0, __float_as_int(v), CTRL, 0xF, 0xF, true));
}
#define DPP_XOR1 0xB1   // quad_perm [1,0,3,2] : lane ^ 1
#define DPP_XOR2 0x4E   // quad_perm [2,3,0,1] : lane ^ 2
#define DPP_ROR8 0x128  // row_ror:8          : lane ^ 8 (within row16)

__device__ __forceinline__ float swz_xor16(float v) {
    // ds_swizzle BitMode: xor_mask=16, and_mask=0x1F -> lane ^ 16 (within 32)
    return __int_as_float(__builtin_amdgcn_ds_swizzle(__float_as_int(v), 0x401F));
}

// NOTE: no min-waves floor! (512,4) forced a 64-VGPR cap -> weight spill ->
// 11.9 GB of scratch re-fetch per dispatch. Let the allocator take ~128.
__global__ __launch_bounds__(TPB) void lstm_fused(
    const float* __restrict__ x,      // [4096,256,32]
    const float* __restrict__ W_ih1,  // [256,32]
    const float* __restrict__ W_hh1,  // [256,64]
    const float* __restrict__ b_ih1,  // [256]
    const float* __restrict__ b_hh1,  // [256]
    const float* __restrict__ W_ih2,  // [128,64]
    const float* __restrict__ W_hh2,  // [128,32]
    const float* __restrict__ b_ih2,  // [128]
    const float* __restrict__ b_hh2,  // [128]
    const float* __restrict__ W_fc1,  // [16,32]
    const float* __restrict__ b_fc1,  // [16]
    const float* __restrict__ W_fc2,  // [1,16]
    const float* __restrict__ b_fc2,  // [1]
    float* __restrict__ out)          // [4096]
{
    const int tid  = threadIdx.x;
    const int lane = tid & 63;
    const int wid  = tid >> 6;
    const int b0   = blockIdx.x * NB;

    // v1 = [x_t(32) | h1(64)], v2 = [h1(64) | h2(32)], double-buffered
    __shared__ float v1s[2 * BUFSZ];
    __shared__ float v2s[2 * BUFSZ];
    __shared__ float hd[NB][16];

    // ---- layer-1 mapping: kq from lane bits {0,1,3}; u from bits {2,4,5}+wid ----
    const int kq = (lane & 3) | (((lane >> 3) & 1) << 2);                       // 0..7
    const int u  = ((lane >> 2) & 1) | (((lane >> 4) & 3) << 1) | (wid << 3);   // 0..63
    // ---- layer-2 mapping: kq2 from lane bits {0,1,3,4}; u2 from bits {2,5}+wid ----
    const int kq2 = (lane & 3) | (((lane >> 3) & 3) << 2);                      // 0..15
    const int u2  = ((lane >> 2) & 1) | (((lane >> 5) & 1) << 1) | (wid << 2);  // 0..31
    const int kp2 = kq2 & 7;

    // ---- weights in registers: all 4 gates of unit u (L1) / u2 (L2), one k-slice ----
    float w1[4][12];
    float bias1[4];
    #pragma unroll
    for (int g = 0; g < 4; ++g) {
        const int r = u + 64 * g;
        bias1[g] = b_ih1[r] + b_hh1[r];
        #pragma unroll
        for (int kk = 0; kk < 12; ++kk) {
            const int k = 12 * kq + kk;
            w1[g][kk] = (k < 32) ? W_ih1[r * 32 + k] : W_hh1[r * 64 + (k - 32)];
        }
    }
    float w2[4][6];
    float bias2[4];
    #pragma unroll
    for (int g = 0; g < 4; ++g) {
        const int r = u2 + 32 * g;
        bias2[g] = b_ih2[r] + b_hh2[r];
        #pragma unroll
        for (int kk = 0; kk < 6; ++kk) {
            const int k = 6 * kq2 + kk;
            w2[g][kk] = (k < 64) ? W_ih2[r * 64 + k] : W_hh2[r * 32 + (k - 64)];
        }
    }

    // ---- init: zero both buffers, stage x0, prefetch x1 ----
    for (int i = tid; i < 2 * BUFSZ; i += TPB) { v1s[i] = 0.f; v2s[i] = 0.f; }
    const int  xb   = tid >> 5, xf = tid & 31;
    const bool xact = tid < NB * F_;   // 256 threads stage x
    const size_t xbase = (size_t)(b0 + xb) * (T_ * F_) + xf;
    float xn = 0.f;
    __syncthreads();
    if (xact) {
        v1s[xb * ROWPAD + xf] = x[xbase];   // x(0) -> buffer 0
        xn = x[xbase + F_];                 // prefetch x(1)
    }
    __syncthreads();

    float c1 = 0.f, c2 = 0.f;

    for (int t = 0; t < T_; ++t) {
        const int cur = t & 1;
        const float* v1c  = v1s + cur * BUFSZ;          // A reads
        float*       v1n  = v1s + (cur ^ 1) * BUFSZ;    // A writes h1, x(t+1)
        const float* v2r  = v2s + (cur ^ 1) * BUFSZ;    // C reads (h1(t) + h2(t-1))
        float*       v2wA = v2s + (cur ^ 1) * BUFSZ;    // A writes h1
        float*       v2wC = v2s + cur * BUFSZ;          // C writes h2

        // ===== layer-1 dots: acc[g][r] accumulates batch b = r ^ kq =====
        float acc[4][8];
        #pragma unroll
        for (int g = 0; g < 4; ++g)
            #pragma unroll
            for (int r = 0; r < 8; ++r) acc[g][r] = 0.f;
        #pragma unroll
        for (int j = 0; j < 3; ++j) {
            #pragma unroll
            for (int r = 0; r < 8; ++r) {
                const float4 v = *(const float4*)&v1c[(r ^ kq) * ROWPAD + 12 * kq + 4 * j];
                #pragma unroll
                for (int g = 0; g < 4; ++g) {
                    acc[g][r] = fmaf(w1[g][4 * j + 0], v.x, acc[g][r]);
                    acc[g][r] = fmaf(w1[g][4 * j + 1], v.y, acc[g][r]);
                    acc[g][r] = fmaf(w1[g][4 * j + 2], v.z, acc[g][r]);
                    acc[g][r] = fmaf(w1[g][4 * j + 3], v.w, acc[g][r]);
                }
            }
        }
        // stage x(t+1) into next buffer; prefetch x(t+2)
        if (xact) {
            v1n[xb * ROWPAD + xf] = xn;
            const int tn = (t + 2 < T_) ? t + 2 : T_ - 1;
            xn = x[xbase + (size_t)tn * F_];
        }
        // ===== in-register k-reduce (lanes kq^1, kq^2, kq^4 hold slots r^1,r^2,r^4) =====
        #pragma unroll
        for (int g = 0; g < 4; ++g) {
            acc[g][0] += dppf<DPP_XOR1>(acc[g][1]);
            acc[g][2] += dppf<DPP_XOR1>(acc[g][3]);
            acc[g][4] += dppf<DPP_XOR1>(acc[g][5]);
            acc[g][6] += dppf<DPP_XOR1>(acc[g][7]);
            acc[g][0] += dppf<DPP_XOR2>(acc[g][2]);
            acc[g][4] += dppf<DPP_XOR2>(acc[g][6]);
            acc[g][0] += dppf<DPP_ROR8>(acc[g][4]);
        }
        // ===== layer-1 combine: this lane owns (unit u, batch b = kq) =====
        {
            const float i_ = sigmoid_fast(acc[0][0] + bias1[0]);
            const float f_ = sigmoid_fast(acc[1][0] + bias1[1]);
            const float g_ = tanh_fast   (acc[2][0] + bias1[2]);
            const float o_ = sigmoid_fast(acc[3][0] + bias1[3]);
            c1 = fmaf(f_, c1, i_ * g_);
            const float h1 = o_ * tanh_fast(c1);
            v1n [kq * ROWPAD + 32 + u] = h1;
            v2wA[kq * ROWPAD + u]      = h1;
        }
        __syncthreads();   // the ONLY barrier per step

        // ===== layer-2 dots: a2[g][r] accumulates batch b = r ^ kp2 =====
        float a2[4][8];
        #pragma unroll
        for (int g = 0; g < 4; ++g)
            #pragma unroll
            for (int r = 0; r < 8; ++r) a2[g][r] = 0.f;
        #pragma unroll
        for (int j = 0; j < 3; ++j) {
            #pragma unroll
            for (int r = 0; r < 8; ++r) {
                const float2 v = *(const float2*)&v2r[(r ^ kp2) * ROWPAD + 6 * kq2 + 2 * j];
                #pragma unroll
                for (int g = 0; g < 4; ++g) {
                    a2[g][r] = fmaf(w2[g][2 * j + 0], v.x, a2[g][r]);
                    a2[g][r] = fmaf(w2[g][2 * j + 1], v.y, a2[g][r]);
                }
            }
        }
        // reduce over 16 k-lanes: 3 DPP halvings + final xor16 via ds_swizzle
        #pragma unroll
        for (int g = 0; g < 4; ++g) {
            a2[g][0] += dppf<DPP_XOR1>(a2[g][1]);
            a2[g][2] += dppf<DPP_XOR1>(a2[g][3]);
            a2[g][4] += dppf<DPP_XOR1>(a2[g][5]);
            a2[g][6] += dppf<DPP_XOR1>(a2[g][7]);
            a2[g][0] += dppf<DPP_XOR2>(a2[g][2]);
            a2[g][4] += dppf<DPP_XOR2>(a2[g][6]);
            a2[g][0] += dppf<DPP_ROR8>(a2[g][4]);
            a2[g][0] += swz_xor16(a2[g][0]);
        }
        // ===== layer-2 combine: lane owns (u2, b = kp2); lanes kq2>=8 are duplicates =====
        {
            const float i_ = sigmoid_fast(a2[0][0] + bias2[0]);
            const float f_ = sigmoid_fast(a2[1][0] + bias2[1]);
            const float g_ = tanh_fast   (a2[2][0] + bias2[2]);
            const float o_ = sigmoid_fast(a2[3][0] + bias2[3]);
            c2 = fmaf(f_, c2, i_ * g_);
            const float h2 = o_ * tanh_fast(c2);
            if (!(kq2 & 8)) v2wC[kp2 * ROWPAD + 64 + u2] = h2;
        }
        // no barrier: next A touches only v1; C(t)'s v2 writes cross next step's barrier
    }

    __syncthreads();
    // ===== head: fc1(16)+relu, fc2(1). Final h2 sits in buffer (T_-1)&1 =====
    const float* v2f = v2s + ((T_ - 1) & 1) * BUFSZ;
    if (tid < NB * 16) {
        const int b = tid >> 4, uu = tid & 15;
        float a = b_fc1[uu];
        #pragma unroll
        for (int k = 0; k < 32; ++k)
            a = fmaf(W_fc1[uu * 32 + k], v2f[b * ROWPAD + 64 + k], a);
        hd[b][uu] = fmaxf(a, 0.f);
    }
    __syncthreads();
    if (tid < NB) {
        float a = b_fc2[0];
        #pragma unroll
        for (int k = 0; k < 16; ++k) a = fmaf(W_fc2[k], hd[tid][k], a);
        out[b0 + tid] = a;
    }
}

extern "C" void kernel_launch(void* const* d_in, const int* in_sizes, int n_in,
                              void* d_out, int out_size, void* d_ws, size_t ws_size,
                              hipStream_t stream) {
    const float* x     = (const float*)d_in[0];
    const float* W_ih1 = (const float*)d_in[1];
    const float* W_hh1 = (const float*)d_in[2];
    const float* b_ih1 = (const float*)d_in[3];
    const float* b_hh1 = (const float*)d_in[4];
    const float* W_ih2 = (const float*)d_in[5];
    const float* W_hh2 = (const float*)d_in[6];
    const float* b_ih2 = (const float*)d_in[7];
    const float* b_hh2 = (const float*)d_in[8];
    const float* W_fc1 = (const float*)d_in[9];
    const float* b_fc1 = (const float*)d_in[10];
    const float* W_fc2 = (const float*)d_in[11];
    const float* b_fc2 = (const float*)d_in[12];
    float* out = (float*)d_out;

    const int B = in_sizes[0] / (T_ * F_);   // 4096
    dim3 grid(B / NB), block(TPB);
    hipLaunchKernelGGL(lstm_fused, grid, block, 0, stream,
                       x, W_ih1, W_hh1, b_ih1, b_hh1,
                       W_ih2, W_hh2, b_ih2, b_hh2,
                       W_fc1, b_fc1, W_fc2, b_fc2, out);
}

// Round 4
// 420.885 us; speedup vs baseline: 9.7702x; 3.5480x over previous
//
#include <hip/hip_runtime.h>

#define T_   256
#define F_   32
#define NBB  16    // batch elements per block
#define TPB  512   // 8 waves
#define IMW  104   // img row width in ushorts (16B-aligned rows, 2-way banks at worst)

typedef __attribute__((ext_vector_type(8))) short bf16x8;
typedef __attribute__((ext_vector_type(4))) float f32x4;
typedef __attribute__((ext_vector_type(4))) unsigned short ush4;

__device__ __forceinline__ float sigmoid_fast(float x){ return __fdividef(1.f, 1.f + __expf(-x)); }
__device__ __forceinline__ float tanh_fast(float x){ float e = __expf(2.f*x); return 1.f - __fdividef(2.f, e + 1.f); }

__device__ __forceinline__ unsigned short bf16_rne(float x){
    unsigned u = __float_as_uint(x);
    u += 0x7FFF + ((u >> 16) & 1);
    return (unsigned short)(u >> 16);
}
__device__ __forceinline__ void bf16_split(float x, unsigned short& h, unsigned short& l){
    h = bf16_rne(x);
    float xr = __uint_as_float(((unsigned)h) << 16);
    l = bf16_rne(x - xr);   // exact residual, then rounded: combined err ~2^-18
}

// build hi/lo bf16 fragments from 8 consecutive f32
__device__ __forceinline__ void make_frags(const float* __restrict__ p8, bf16x8& fh, bf16x8& fl){
    #pragma unroll
    for (int e = 0; e < 8; ++e){
        unsigned short h, l; bf16_split(p8[e], h, l);
        fh[e] = (short)h; fl[e] = (short)l;
    }
}

__global__ __launch_bounds__(TPB) void lstm_mfma(
    const float* __restrict__ x,      // [4096,256,32]
    const float* __restrict__ W_ih1,  // [256,32]
    const float* __restrict__ W_hh1,  // [256,64]
    const float* __restrict__ b_ih1,  // [256]
    const float* __restrict__ b_hh1,  // [256]
    const float* __restrict__ W_ih2,  // [128,64]
    const float* __restrict__ W_hh2,  // [128,32]
    const float* __restrict__ b_ih2,  // [128]
    const float* __restrict__ b_hh2,  // [128]
    const float* __restrict__ W_fc1,  // [16,32]
    const float* __restrict__ b_fc1,  // [16]
    const float* __restrict__ W_fc2,  // [1,16]
    const float* __restrict__ b_fc2,  // [1]
    float* __restrict__ out)          // [4096]
{
    const int tid  = threadIdx.x;
    const int lane = tid & 63;
    const int wid  = tid >> 6;        // 0..7
    const int bb   = lane & 15;       // fragment outer index = batch
    const int kg   = (lane >> 4) & 3; // k-group (8 elems each)
    const int b0   = blockIdx.x * NBB;

    // img1 = [x(32) | h1(64)], img2 = [h1(64) | h2(32)]; hi/lo bf16, double-buffered
    __shared__ __align__(16) unsigned short i1h[2][NBB][IMW], i1l[2][NBB][IMW];
    __shared__ __align__(16) unsigned short i2h[2][NBB][IMW], i2l[2][NBB][IMW];
    __shared__ __align__(16) float pre2[NBB][132];   // L2 gate preacts (128 rows + pad)
    __shared__ float hfin[NBB][32];                  // final h2 (f32)
    __shared__ float hd[NBB][16];

    // ================= prologue: weight fragments =================
    // L1 waves (wid 0-3): gate g tile = rows 64g+16wid; unit u = 16wid + 4kg + reg.
    // L2 waves (wid 4-7): j=wid-4, tiles rows {32j, 32j+16}.
    bf16x8 wfh[4][3], wfl[4][3];
    f32x4  bfr[4];
    if (wid < 4){
        #pragma unroll
        for (int g = 0; g < 4; ++g){
            const int r = 64*g + 16*wid + bb;
            make_frags(&W_ih1[r*32 +      8*kg], wfh[g][0], wfl[g][0]);
            make_frags(&W_hh1[r*64 +      8*kg], wfh[g][1], wfl[g][1]);
            make_frags(&W_hh1[r*64 + 32 + 8*kg], wfh[g][2], wfl[g][2]);
            #pragma unroll
            for (int q = 0; q < 4; ++q){
                const int row = 64*g + 16*wid + 4*kg + q;
                bfr[g][q] = b_ih1[row] + b_hh1[row];
            }
        }
    } else {
        const int j = wid - 4;
        #pragma unroll
        for (int tt = 0; tt < 2; ++tt){
            const int r = 32*j + 16*tt + bb;
            make_frags(&W_ih2[r*64 +      8*kg], wfh[tt][0], wfl[tt][0]);
            make_frags(&W_ih2[r*64 + 32 + 8*kg], wfh[tt][1], wfl[tt][1]);
            make_frags(&W_hh2[r*32 +      8*kg], wfh[tt][2], wfl[tt][2]);
        }
    }
    // L2 combine bias (all threads): pair (u2 = tid>>4, b2 = tid&15)
    const int u2 = tid >> 4, b2 = tid & 15;
    float bias2[4];
    #pragma unroll
    for (int g = 0; g < 4; ++g) bias2[g] = b_ih2[u2 + 32*g] + b_hh2[u2 + 32*g];

    // ================= prologue: zero images, stage x(0) =================
    for (int i = tid; i < 2*NBB*IMW/2; i += TPB){
        ((unsigned*)i1h)[i] = 0u; ((unsigned*)i1l)[i] = 0u;
        ((unsigned*)i2h)[i] = 0u; ((unsigned*)i2l)[i] = 0u;
    }
    const int xbb = tid >> 5, xff = tid & 31;
    const size_t xbase = (size_t)(b0 + xbb) * (T_*F_) + xff;
    __syncthreads();
    {
        unsigned short h, l; bf16_split(x[xbase], h, l);
        i1h[0][xbb][xff] = h; i1l[0][xbb][xff] = l;
    }
    float xn = x[xbase + F_];   // x(1)
    __syncthreads();

    f32x4 acc[4];
    float c1[4] = {0.f,0.f,0.f,0.f};
    float c2 = 0.f;

    // ================= main loop: L2 lags L1 by one step =================
    for (int t = 0; t <= T_; ++t){
        const int cur = t & 1, nxt = cur ^ 1;

        // ---------- phase 1: MFMA ----------
        if (wid < 4){
            if (t < T_){
                bf16x8 vh[3], vl[3];
                const unsigned short* ph = &i1h[cur][0][0] + bb*IMW + 8*kg;
                const unsigned short* pl = &i1l[cur][0][0] + bb*IMW + 8*kg;
                #pragma unroll
                for (int kb = 0; kb < 3; ++kb){
                    vh[kb] = *(const bf16x8*)(ph + 32*kb);
                    vl[kb] = *(const bf16x8*)(pl + 32*kb);
                }
                #pragma unroll
                for (int g = 0; g < 4; ++g){
                    f32x4 a = bfr[g];
                    #pragma unroll
                    for (int kb = 0; kb < 3; ++kb){
                        a = __builtin_amdgcn_mfma_f32_16x16x32_bf16(wfh[g][kb], vh[kb], a, 0,0,0);
                        a = __builtin_amdgcn_mfma_f32_16x16x32_bf16(wfh[g][kb], vl[kb], a, 0,0,0);
                        a = __builtin_amdgcn_mfma_f32_16x16x32_bf16(wfl[g][kb], vh[kb], a, 0,0,0);
                    }
                    acc[g] = a;
                }
            }
        } else {
            if (t > 0){
                const int j = wid - 4;
                bf16x8 vh[3], vl[3];
                const unsigned short* ph = &i2h[cur][0][0] + bb*IMW + 8*kg;
                const unsigned short* pl = &i2l[cur][0][0] + bb*IMW + 8*kg;
                #pragma unroll
                for (int kb = 0; kb < 3; ++kb){
                    vh[kb] = *(const bf16x8*)(ph + 32*kb);
                    vl[kb] = *(const bf16x8*)(pl + 32*kb);
                }
                f32x4 a0 = {0.f,0.f,0.f,0.f}, a1 = {0.f,0.f,0.f,0.f};
                #pragma unroll
                for (int kb = 0; kb < 3; ++kb){
                    a0 = __builtin_amdgcn_mfma_f32_16x16x32_bf16(wfh[0][kb], vh[kb], a0, 0,0,0);
                    a0 = __builtin_amdgcn_mfma_f32_16x16x32_bf16(wfh[0][kb], vl[kb], a0, 0,0,0);
                    a0 = __builtin_amdgcn_mfma_f32_16x16x32_bf16(wfl[0][kb], vh[kb], a0, 0,0,0);
                    a1 = __builtin_amdgcn_mfma_f32_16x16x32_bf16(wfh[1][kb], vh[kb], a1, 0,0,0);
                    a1 = __builtin_amdgcn_mfma_f32_16x16x32_bf16(wfh[1][kb], vl[kb], a1, 0,0,0);
                    a1 = __builtin_amdgcn_mfma_f32_16x16x32_bf16(wfl[1][kb], vh[kb], a1, 0,0,0);
                }
                // D: col=lane&15=batch, rows = R + 4*kg + reg (4 consecutive) -> b128 store
                *(f32x4*)&pre2[bb][32*j      + 4*kg] = a0;
                *(f32x4*)&pre2[bb][32*j + 16 + 4*kg] = a1;
            }
        }
        __syncthreads();   // pre2 ready; img[cur] reads done

        // ---------- phase 2: combine + write img[nxt] ----------
        if (wid < 4 && t < T_){
            // lane owns units u0..u0+3 (u0 = 16wid+4kg) of batch bb; gates in acc[g][q]
            unsigned short hh[4], hl[4];
            #pragma unroll
            for (int q = 0; q < 4; ++q){
                const float i_ = sigmoid_fast(acc[0][q]);
                const float f_ = sigmoid_fast(acc[1][q]);
                const float g_ = tanh_fast   (acc[2][q]);
                const float o_ = sigmoid_fast(acc[3][q]);
                c1[q] = fmaf(f_, c1[q], i_ * g_);
                const float h = o_ * tanh_fast(c1[q]);
                bf16_split(h, hh[q], hl[q]);
            }
            const int u0 = 16*wid + 4*kg;
            ush4 phv; phv[0]=hh[0]; phv[1]=hh[1]; phv[2]=hh[2]; phv[3]=hh[3];
            ush4 plv; plv[0]=hl[0]; plv[1]=hl[1]; plv[2]=hl[2]; plv[3]=hl[3];
            *(ush4*)&i1h[nxt][bb][32 + u0] = phv;
            *(ush4*)&i1l[nxt][bb][32 + u0] = plv;
            *(ush4*)&i2h[nxt][bb][u0]      = phv;
            *(ush4*)&i2l[nxt][bb][u0]      = plv;
        }
        if (t > 0){
            const float g0 = pre2[b2][u2      ] + bias2[0];
            const float g1 = pre2[b2][u2 + 32 ] + bias2[1];
            const float g2 = pre2[b2][u2 + 64 ] + bias2[2];
            const float g3 = pre2[b2][u2 + 96 ] + bias2[3];
            const float i_ = sigmoid_fast(g0);
            const float f_ = sigmoid_fast(g1);
            const float gg = tanh_fast   (g2);
            const float o_ = sigmoid_fast(g3);
            c2 = fmaf(f_, c2, i_ * gg);
            const float h2v = o_ * tanh_fast(c2);
            unsigned short h, l; bf16_split(h2v, h, l);
            i2h[nxt][b2][64 + u2] = h;
            i2l[nxt][b2][64 + u2] = l;
            if (t == T_) hfin[b2][u2] = h2v;
        }
        if (t < T_ - 1){
            unsigned short h, l; bf16_split(xn, h, l);
            i1h[nxt][xbb][xff] = h; i1l[nxt][xbb][xff] = l;
            const int tn = (t + 2 < T_) ? t + 2 : T_ - 1;
            xn = x[xbase + (size_t)tn * F_];
        }
        __syncthreads();
    }

    // ================= head =================
    if (tid < NBB * 16){
        const int b = tid >> 4, j2 = tid & 15;
        float a = b_fc1[j2];
        #pragma unroll
        for (int k = 0; k < 32; ++k) a = fmaf(W_fc1[j2*32 + k], hfin[b][k], a);
        hd[b][j2] = fmaxf(a, 0.f);
    }
    __syncthreads();
    if (tid < NBB){
        float a = b_fc2[0];
        #pragma unroll
        for (int k = 0; k < 16; ++k) a = fmaf(W_fc2[k], hd[tid][k], a);
        out[b0 + tid] = a;
    }
}

extern "C" void kernel_launch(void* const* d_in, const int* in_sizes, int n_in,
                              void* d_out, int out_size, void* d_ws, size_t ws_size,
                              hipStream_t stream) {
    const float* x     = (const float*)d_in[0];
    const float* W_ih1 = (const float*)d_in[1];
    const float* W_hh1 = (const float*)d_in[2];
    const float* b_ih1 = (const float*)d_in[3];
    const float* b_hh1 = (const float*)d_in[4];
    const float* W_ih2 = (const float*)d_in[5];
    const float* W_hh2 = (const float*)d_in[6];
    const float* b_ih2 = (const float*)d_in[7];
    const float* b_hh2 = (const float*)d_in[8];
    const float* W_fc1 = (const float*)d_in[9];
    const float* b_fc1 = (const float*)d_in[10];
    const float* W_fc2 = (const float*)d_in[11];
    const float* b_fc2 = (const float*)d_in[12];
    float* out = (float*)d_out;

    const int B = in_sizes[0] / (T_ * F_);   // 4096
    dim3 grid(B / NBB), block(TPB);          // 256 blocks = 1/CU
    hipLaunchKernelGGL(lstm_mfma, grid, block, 0, stream,
                       x, W_ih1, W_hh1, b_ih1, b_hh1,
                       W_ih2, W_hh2, b_ih2, b_hh2,
                       W_fc1, b_fc1, W_fc2, b_fc2, out);
}